// Round 12
// baseline (241.018 us; speedup 1.0000x reference)
//
#include <hip/hip_runtime.h>
#include <stdint.h>

constexpr int NN = 100000;   // nodes
constexpr int NE = 1600000;  // edges
constexpr int D  = 64;       // feature dim
constexpr int DO = 128;      // output dim

constexpr int BSHIFT = 9;                       // 512 nodes per bucket
constexpr int BMASK  = (1 << BSHIFT) - 1;       // 511
constexpr int NBKT   = (NN + BMASK) / (1 << BSHIFT);  // 196
constexpr int CHUNK  = 4096;                    // edges per place/hist block
constexpr int NCHUNK_E = (NE + CHUNK - 1) / CHUNK;    // 391
constexpr int IMG_CAP = 16384;                  // max edges/bucket (mean 8192)

// ---------------------------------------------------------------------------
// Detect whether edge_index buffer is int64 or int32 (odd words all zero).
// Also zeros bktcnt (fused to save a launch).
__global__ void detect_i64(const uint32_t* __restrict__ e, int* __restrict__ flag,
                           int* __restrict__ bktcnt) {
    __shared__ uint32_t acc;
    if (threadIdx.x == 0) acc = 0u;
    __syncthreads();
    uint32_t w = e[2 * threadIdx.x + 1];
    atomicOr(&acc, w);
    if (threadIdx.x < NBKT) bktcnt[threadIdx.x] = 0;
    __syncthreads();
    if (threadIdx.x == 0) *flag = (acc == 0u) ? 1 : 0;
}

// ---------------------------------------------------------------------------
// Pass 1a: coarse histogram (196 buckets), LDS-aggregated.
__global__ __launch_bounds__(256) void hist_kernel(const void* __restrict__ e,
                                                   const int* __restrict__ flag,
                                                   int* __restrict__ bktcnt) {
    __shared__ int cnt[256];
    const int tid = threadIdx.x;
    cnt[tid] = 0;
    __syncthreads();
    const int f = *flag;
    const int base = blockIdx.x * CHUNK;
    const int lim = min(CHUNK, NE - base);
    for (int t = tid; t < lim; t += 256) {
        int d = f ? (int)((const long long*)e)[NE + base + t]
                  : ((const int*)e)[NE + base + t];
        atomicAdd(&cnt[d >> BSHIFT], 1);
    }
    __syncthreads();
    if (tid < NBKT && cnt[tid]) atomicAdd(&bktcnt[tid], cnt[tid]);
}

// Pass 1b: scan 196 bucket sizes -> gbase[NBKT+1], init gcursor.
__global__ void scan_bkt(const int* __restrict__ bktcnt, int* __restrict__ gbase,
                         int* __restrict__ gcursor) {
    __shared__ int s[256];
    __shared__ int o[257];
    const int tid = threadIdx.x;
    s[tid] = (tid < NBKT) ? bktcnt[tid] : 0;
    __syncthreads();
    if (tid == 0) {
        int run = 0;
        for (int bkt = 0; bkt < NBKT; ++bkt) { o[bkt] = run; run += s[bkt]; }
        o[NBKT] = run;
    }
    __syncthreads();
    if (tid < NBKT) { gbase[tid] = o[tid]; gcursor[tid] = o[tid]; }
    if (tid == 0) gbase[NBKT] = o[NBKT];
}

// Pass 2: bin 4096 edges into 196 buckets via LDS, flush coalesced runs.
// Packed word: (src << 9) | (dst & 511).  src < 2^17 -> fits 26 bits.
__global__ __launch_bounds__(256) void place_kernel(const void* __restrict__ e,
                                                    const int* __restrict__ flag,
                                                    int* __restrict__ gcursor,
                                                    uint32_t* __restrict__ bkt) {
    __shared__ int cnt[256];
    __shared__ int lbase[256];
    __shared__ int lcur[256];
    __shared__ int gb[256];
    __shared__ int sc[2][256];
    __shared__ uint32_t stage[CHUNK];   // 16 KB
    __shared__ uint8_t  sbkt[CHUNK];    // 4 KB
    const int tid = threadIdx.x;
    const int f = *flag;
    const int base = blockIdx.x * CHUNK;
    const int lim = min(CHUNK, NE - base);

    cnt[tid] = 0;
    __syncthreads();

    int      myb[16];
    uint32_t myp[16];
#pragma unroll
    for (int k = 0; k < 16; ++k) {
        const int t = tid + (k << 8);
        myb[k] = -1;
        if (t < lim) {
            int s, d;
            if (f) {
                s = (int)((const long long*)e)[base + t];
                d = (int)((const long long*)e)[NE + base + t];
            } else {
                s = ((const int*)e)[base + t];
                d = ((const int*)e)[NE + base + t];
            }
            const int bb = d >> BSHIFT;
            myb[k] = bb;
            myp[k] = ((uint32_t)s << BSHIFT) | (uint32_t)(d & BMASK);
            atomicAdd(&cnt[bb], 1);
        }
    }
    __syncthreads();

    // exclusive scan of cnt over 256 entries (Hillis-Steele)
    const int v = cnt[tid];
    int pb = 0;
    sc[0][tid] = v;
    __syncthreads();
#pragma unroll
    for (int off = 1; off < 256; off <<= 1) {
        int t = sc[pb][tid] + ((tid >= off) ? sc[pb][tid - off] : 0);
        pb ^= 1;
        sc[pb][tid] = t;
        __syncthreads();
    }
    lbase[tid] = sc[pb][tid] - v;   // exclusive
    lcur[tid]  = sc[pb][tid] - v;
    if (tid < NBKT && v > 0) gb[tid] = atomicAdd(&gcursor[tid], v);
    __syncthreads();

#pragma unroll
    for (int k = 0; k < 16; ++k) {
        if (myb[k] >= 0) {
            const int p = atomicAdd(&lcur[myb[k]], 1);
            stage[p] = myp[k];
            sbkt[p] = (uint8_t)myb[k];
        }
    }
    __syncthreads();

    for (int i = tid; i < lim; i += 256) {
        const int bb = sbkt[i];
        bkt[gb[bb] + (i - lbase[bb])] = stage[i];
    }
}

// Pass 3: one block per bucket. Exact-dst counting sort fully in LDS,
// coalesced CSR image copy-out + rowptr + dinv.
__global__ __launch_bounds__(512) void build_kernel(const uint32_t* __restrict__ bkt,
                                                    const int* __restrict__ gbase,
                                                    int* __restrict__ rowptr,
                                                    float* __restrict__ dinv,
                                                    int* __restrict__ csr) {
    __shared__ int cnt[512];
    __shared__ int sc[2][512];
    __shared__ uint32_t img[IMG_CAP];   // 64 KB
    const int tid = threadIdx.x;
    const int b = blockIdx.x;
    const int beg = gbase[b];
    const int end = gbase[b + 1];
    const int n = end - beg;
    const int node0 = b << BSHIFT;
    const int nnodes = min(512, NN - node0);

    cnt[tid] = 0;
    __syncthreads();
    for (int i = tid; i < n; i += 512) atomicAdd(&cnt[bkt[beg + i] & BMASK], 1);
    __syncthreads();

    const int deg = cnt[tid];
    int pb = 0;
    sc[0][tid] = deg;
    __syncthreads();
#pragma unroll
    for (int off = 1; off < 512; off <<= 1) {
        int t = sc[pb][tid] + ((tid >= off) ? sc[pb][tid - off] : 0);
        pb ^= 1;
        sc[pb][tid] = t;
        __syncthreads();
    }
    const int excl = sc[pb][tid] - deg;

    if (tid < nnodes) {
        rowptr[node0 + tid] = beg + excl;
        dinv[node0 + tid] = 1.0f / fmaxf((float)deg, 1.0f);
    }
    if (b == 0 && tid == 0) rowptr[NN] = NE;

    __syncthreads();
    cnt[tid] = excl;   // reuse as cursor
    __syncthreads();
    for (int i = tid; i < n; i += 512) {
        const uint32_t w = bkt[beg + i];
        const int p = atomicAdd(&cnt[w & BMASK], 1);
        img[p] = (int)(w >> BSHIFT);
    }
    __syncthreads();
    for (int i = tid; i < n; i += 512) csr[beg + i] = (int)img[i];
}

// ---------------------------------------------------------------------------
// bf16 helpers.  Packed u32 holds 2 bf16 (lo = even elem, hi = odd elem).
__device__ __forceinline__ float bflo(uint32_t v) { return __uint_as_float(v << 16); }
__device__ __forceinline__ float bfhi(uint32_t v) { return __uint_as_float(v & 0xffff0000u); }
// Approximate high element: keep low 16 bits as extra mantissa (rel err < 2^-7
// on this addend only). Saves the v_and per pair in the hot accumulate loop.
__device__ __forceinline__ float bfhi_approx(uint32_t v) { return __uint_as_float(v); }
__device__ __forceinline__ uint32_t bf16rn(float f) {   // round-to-nearest-even
    uint32_t u = __float_as_uint(f);
    return (u + 0x7fffu + ((u >> 16) & 1u)) >> 16;
}
__device__ __forceinline__ uint32_t bfpack(float lo, float hi) {
    return bf16rn(lo) | (bf16rn(hi) << 16);
}

// x (f32) -> packed bf16
__global__ void cvt_bf16(const float4* __restrict__ x4, uint2* __restrict__ o2) {
    const int n = NN * 16;
    for (int i = blockIdx.x * blockDim.x + threadIdx.x; i < n;
         i += gridDim.x * blockDim.x) {
        const float4 v = x4[i];
        uint2 o;
        o.x = bfpack(v.x, v.y);
        o.y = bfpack(v.z, v.w);
        o2[i] = o;
    }
}

// ---------------------------------------------------------------------------
// Fused WL layer on bf16 rows (128 B/row).  TWO nodes per wave: each 32-lane
// half owns one node, 4 edge-groups of 8 lanes; lane reads one 16B granule
// (8 bf16, uint4) per edge.  4-DEEP unroll: 32 outstanding row-gathers per
// wave (latency cover for random L2/L3 hits).  deg~16 -> one main iteration
// per group, remainder loop for deg%16.  Reduce: 2 shfl levels (8,16).
// MODE 0: out = relu(0.5*(h + agg*dinv));  MODE 1: out = h + relu(...)
__device__ __forceinline__ void acc_bf8(float4& p, float4& r, const uint4 v) {
    p.x += bflo(v.x); p.y += bfhi_approx(v.x);
    p.z += bflo(v.y); p.w += bfhi_approx(v.y);
    r.x += bflo(v.z); r.y += bfhi_approx(v.z);
    r.z += bflo(v.w); r.w += bfhi_approx(v.w);
}

template <int MODE>
__global__ __launch_bounds__(256) void wl_layer_bf(
    const uint4* __restrict__ hb, const int* __restrict__ rowptr,
    const int* __restrict__ csr_src, const float* __restrict__ dinv,
    uint4* __restrict__ outp) {
    const int wid = (blockIdx.x * blockDim.x + threadIdx.x) >> 6;
    const int lane = threadIdx.x & 63;
    const int half = lane >> 5;          // node slot within wave (0..1)
    const int g = (lane >> 3) & 3;       // edge group within half (0..3)
    const int q = lane & 7;              // 16B granule within row (0..7)
    const int node = wid * 2 + half;
    if (node >= NN) return;

    const int beg = rowptr[node];
    const int end = rowptr[node + 1];

    float4 a0 = make_float4(0.f, 0.f, 0.f, 0.f);
    float4 a1 = make_float4(0.f, 0.f, 0.f, 0.f);
    float4 b0 = make_float4(0.f, 0.f, 0.f, 0.f);
    float4 b1 = make_float4(0.f, 0.f, 0.f, 0.f);
    int e = beg + g;
    // 4-deep: issue 4 index loads, then 4 row gathers, then consume.
    for (; e + 12 < end; e += 16) {
        const int s0 = csr_src[e];
        const int s1 = csr_src[e + 4];
        const int s2 = csr_src[e + 8];
        const int s3 = csr_src[e + 12];
        const uint4 v0 = hb[(size_t)s0 * 8 + q];
        const uint4 v1 = hb[(size_t)s1 * 8 + q];
        const uint4 v2 = hb[(size_t)s2 * 8 + q];
        const uint4 v3 = hb[(size_t)s3 * 8 + q];
        acc_bf8(a0, a1, v0);
        acc_bf8(b0, b1, v1);
        acc_bf8(a0, a1, v2);
        acc_bf8(b0, b1, v3);
    }
    for (; e < end; e += 4) {
        const uint4 v = hb[(size_t)csr_src[e] * 8 + q];
        acc_bf8(a0, a1, v);
    }
    a0.x += b0.x; a0.y += b0.y; a0.z += b0.z; a0.w += b0.w;
    a1.x += b1.x; a1.y += b1.y; a1.z += b1.z; a1.w += b1.w;

    // reduce across the 4 groups of this half (lanes differing in bits 3,4)
#pragma unroll
    for (int off = 8; off < 32; off <<= 1) {
        a0.x += __shfl_xor(a0.x, off, 64);
        a0.y += __shfl_xor(a0.y, off, 64);
        a0.z += __shfl_xor(a0.z, off, 64);
        a0.w += __shfl_xor(a0.w, off, 64);
        a1.x += __shfl_xor(a1.x, off, 64);
        a1.y += __shfl_xor(a1.y, off, 64);
        a1.z += __shfl_xor(a1.z, off, 64);
        a1.w += __shfl_xor(a1.w, off, 64);
    }
    if (g == 0) {
        const float di = dinv[node];
        const uint4 sv = hb[(size_t)node * 8 + q];
        const float s0 = bflo(sv.x), s1 = bfhi(sv.x);
        const float s2 = bflo(sv.y), s3 = bfhi(sv.y);
        const float s4 = bflo(sv.z), s5 = bfhi(sv.z);
        const float s6 = bflo(sv.w), s7 = bfhi(sv.w);
        float r0, r1, r2, r3, r4, r5, r6, r7;
        if (MODE == 0) {
            r0 = fmaxf(0.5f * (s0 + a0.x * di), 0.f);
            r1 = fmaxf(0.5f * (s1 + a0.y * di), 0.f);
            r2 = fmaxf(0.5f * (s2 + a0.z * di), 0.f);
            r3 = fmaxf(0.5f * (s3 + a0.w * di), 0.f);
            r4 = fmaxf(0.5f * (s4 + a1.x * di), 0.f);
            r5 = fmaxf(0.5f * (s5 + a1.y * di), 0.f);
            r6 = fmaxf(0.5f * (s6 + a1.z * di), 0.f);
            r7 = fmaxf(0.5f * (s7 + a1.w * di), 0.f);
        } else {
            r0 = s0 + fmaxf(0.5f * (s0 + a0.x * di), 0.f);
            r1 = s1 + fmaxf(0.5f * (s1 + a0.y * di), 0.f);
            r2 = s2 + fmaxf(0.5f * (s2 + a0.z * di), 0.f);
            r3 = s3 + fmaxf(0.5f * (s3 + a0.w * di), 0.f);
            r4 = s4 + fmaxf(0.5f * (s4 + a1.x * di), 0.f);
            r5 = s5 + fmaxf(0.5f * (s5 + a1.y * di), 0.f);
            r6 = s6 + fmaxf(0.5f * (s6 + a1.z * di), 0.f);
            r7 = s7 + fmaxf(0.5f * (s7 + a1.w * di), 0.f);
        }
        uint4 o;
        o.x = bfpack(r0, r1);
        o.y = bfpack(r2, r3);
        o.z = bfpack(r4, r5);
        o.w = bfpack(r6, r7);
        outp[(size_t)node * 8 + q] = o;
    }
}

// ---------------------------------------------------------------------------
// out = h @ W + b.  Tiled LDS GEMM; h arrives as packed bf16 (final layer
// output), unpacked exactly to f32 during LDS staging.
constexpr int TROWS = 32;
constexpr int NTILE = NN / TROWS;   // 3125 exact

__device__ __forceinline__ void fma4(float4& acc, float s, const float4& wv) {
    acc.x = fmaf(s, wv.x, acc.x);
    acc.y = fmaf(s, wv.y, acc.y);
    acc.z = fmaf(s, wv.z, acc.z);
    acc.w = fmaf(s, wv.w, acc.w);
}

__global__ __launch_bounds__(256, 4) void matmul_kernel(
    const uint2* __restrict__ hb2, const float4* __restrict__ W4,
    const float4* __restrict__ b4, float4* __restrict__ out4) {
    __shared__ __align__(16) float Ws[D * DO];      // 32 KB, [k][j]
    __shared__ __align__(16) float Hs[TROWS * D];   // 8 KB, [row][k]
    const int tid = threadIdx.x;

    {
        float4* ws4 = (float4*)Ws;
#pragma unroll
        for (int i = 0; i < (D * DO / 4) / 256; ++i)   // 8
            ws4[tid + i * 256] = W4[tid + i * 256];
    }
    const int cg = tid & 31;    // col group: cols cg*4..cg*4+3
    const int rs = tid >> 5;    // row slot: rows rs*4..rs*4+3
    const float4 bv = b4[cg];

    for (int tile = blockIdx.x; tile < NTILE; tile += gridDim.x) {
        const int row0 = tile * TROWS;
        __syncthreads();   // Hs safe to overwrite
        {
            // 32 rows x 16 uint2/row = 512 granules; granule i -> float4 Hs[i]
            float4* hs4 = (float4*)Hs;
#pragma unroll
            for (int i = 0; i < 2; ++i) {
                const int idx = tid + i * 256;          // 0..511
                const uint2 v = hb2[(size_t)row0 * 16 + idx];
                hs4[idx] = make_float4(bflo(v.x), bfhi(v.x), bflo(v.y), bfhi(v.y));
            }
        }
        __syncthreads();

        float4 acc0 = bv, acc1 = bv, acc2 = bv, acc3 = bv;
        const float4* hra = (const float4*)(Hs + (rs * 4 + 0) * D);
        const float4* hrb = (const float4*)(Hs + (rs * 4 + 1) * D);
        const float4* hrc = (const float4*)(Hs + (rs * 4 + 2) * D);
        const float4* hrd = (const float4*)(Hs + (rs * 4 + 3) * D);
        const float4* wsc = (const float4*)Ws + cg;     // stride 32 f4 per k
#pragma unroll
        for (int k4 = 0; k4 < 16; ++k4) {
            const float4 ha = hra[k4];
            const float4 hb = hrb[k4];
            const float4 hc = hrc[k4];
            const float4 hd = hrd[k4];
            const float4 w0 = wsc[(k4 * 4 + 0) * 32];
            const float4 w1 = wsc[(k4 * 4 + 1) * 32];
            const float4 w2 = wsc[(k4 * 4 + 2) * 32];
            const float4 w3 = wsc[(k4 * 4 + 3) * 32];
            fma4(acc0, ha.x, w0); fma4(acc0, ha.y, w1);
            fma4(acc0, ha.z, w2); fma4(acc0, ha.w, w3);
            fma4(acc1, hb.x, w0); fma4(acc1, hb.y, w1);
            fma4(acc1, hb.z, w2); fma4(acc1, hb.w, w3);
            fma4(acc2, hc.x, w0); fma4(acc2, hc.y, w1);
            fma4(acc2, hc.z, w2); fma4(acc2, hc.w, w3);
            fma4(acc3, hd.x, w0); fma4(acc3, hd.y, w1);
            fma4(acc3, hd.z, w2); fma4(acc3, hd.w, w3);
        }
        const int orow = row0 + rs * 4;
        out4[(size_t)(orow + 0) * 32 + cg] = acc0;
        out4[(size_t)(orow + 1) * 32 + cg] = acc1;
        out4[(size_t)(orow + 2) * 32 + cg] = acc2;
        out4[(size_t)(orow + 3) * 32 + cg] = acc3;
    }
}

// ---------------------------------------------------------------------------
extern "C" void kernel_launch(void* const* d_in, const int* in_sizes, int n_in,
                              void* d_out, int out_size, void* d_ws, size_t ws_size,
                              hipStream_t stream) {
    const float* x     = (const float*)d_in[0];
    const void*  edges = d_in[1];
    const float* W     = (const float*)d_in[2];
    const float* b     = (const float*)d_in[3];
    float* out = (float*)d_out;

    char* ws = (char*)d_ws;
    const size_t SZ_BF = (size_t)NN * D * 2;   // 12,800,000 bytes (bf16 rows)
    uint8_t*  xb      = (uint8_t*)ws;                                  // bf16 x
    uint8_t*  hBb     = (uint8_t*)(ws + SZ_BF);
    uint8_t*  hAb     = (uint8_t*)(ws + 2 * SZ_BF);
    uint32_t* bkt     = (uint32_t*)(ws + 3 * SZ_BF);                   // NE u32
    int*      csr     = (int*)(ws + 3 * SZ_BF + (size_t)NE * 4);       // NE ints
    int*      rowptr  = (int*)(ws + 3 * SZ_BF + (size_t)NE * 8);       // NN+1
    float*    dinv    = (float*)(rowptr + NN + 8);                     // NN
    int*      bktcnt  = (int*)(dinv + NN);                             // NBKT
    int*      gbase   = bktcnt + NBKT;                                 // NBKT+1
    int*      gcursor = gbase + NBKT + 1;                              // NBKT
    int*      flag    = gcursor + NBKT;

    const dim3 B(256);

    detect_i64<<<1, 256, 0, stream>>>((const uint32_t*)edges, flag, bktcnt);
    hist_kernel<<<NCHUNK_E, B, 0, stream>>>(edges, flag, bktcnt);
    scan_bkt<<<1, 256, 0, stream>>>(bktcnt, gbase, gcursor);
    place_kernel<<<NCHUNK_E, B, 0, stream>>>(edges, flag, gcursor, bkt);
    build_kernel<<<NBKT, 512, 0, stream>>>(bkt, gbase, rowptr, dinv, csr);

    cvt_bf16<<<2048, B, 0, stream>>>((const float4*)x, (uint2*)xb);

    // 2 nodes per wave -> NN/2 waves -> /4 waves per block = 12500 blocks
    const int LG = (NN / 2 + 3) / 4;   // 12500
    // L0: xb -> hAb; L1: hAb -> hBb; L2: hBb -> hAb; L3: hAb -> hBb (all bf16)
    wl_layer_bf<0><<<LG, B, 0, stream>>>((const uint4*)xb,  rowptr, csr, dinv, (uint4*)hAb);
    wl_layer_bf<1><<<LG, B, 0, stream>>>((const uint4*)hAb, rowptr, csr, dinv, (uint4*)hBb);
    wl_layer_bf<1><<<LG, B, 0, stream>>>((const uint4*)hBb, rowptr, csr, dinv, (uint4*)hAb);
    wl_layer_bf<1><<<LG, B, 0, stream>>>((const uint4*)hAb, rowptr, csr, dinv, (uint4*)hBb);

    matmul_kernel<<<1024, B, 0, stream>>>((const uint2*)hBb, (const float4*)W,
                                          (const float4*)b, (float4*)out);
}

// Round 13
// 228.232 us; speedup vs baseline: 1.0560x; 1.0560x over previous
//
#include <hip/hip_runtime.h>
#include <stdint.h>

constexpr int NN = 100000;   // nodes
constexpr int NE = 1600000;  // edges
constexpr int D  = 64;       // feature dim
constexpr int DO = 128;      // output dim

constexpr int BSHIFT = 9;                       // 512 nodes per bucket
constexpr int BMASK  = (1 << BSHIFT) - 1;       // 511
constexpr int NBKT   = (NN + BMASK) / (1 << BSHIFT);  // 196
constexpr int CHUNK  = 4096;                    // edges per place/hist block
constexpr int NCHUNK_E = (NE + CHUNK - 1) / CHUNK;    // 391
constexpr int IMG_CAP = 16384;                  // max edges/bucket (mean 8192)

// ---------------------------------------------------------------------------
// Detect whether edge_index buffer is int64 or int32 (odd words all zero).
// Also zeros bktcnt (fused to save a launch).
__global__ void detect_i64(const uint32_t* __restrict__ e, int* __restrict__ flag,
                           int* __restrict__ bktcnt) {
    __shared__ uint32_t acc;
    if (threadIdx.x == 0) acc = 0u;
    __syncthreads();
    uint32_t w = e[2 * threadIdx.x + 1];
    atomicOr(&acc, w);
    if (threadIdx.x < NBKT) bktcnt[threadIdx.x] = 0;
    __syncthreads();
    if (threadIdx.x == 0) *flag = (acc == 0u) ? 1 : 0;
}

// ---------------------------------------------------------------------------
// Pass 1a: coarse histogram (196 buckets), LDS-aggregated.
__global__ __launch_bounds__(256) void hist_kernel(const void* __restrict__ e,
                                                   const int* __restrict__ flag,
                                                   int* __restrict__ bktcnt) {
    __shared__ int cnt[256];
    const int tid = threadIdx.x;
    cnt[tid] = 0;
    __syncthreads();
    const int f = *flag;
    const int base = blockIdx.x * CHUNK;
    const int lim = min(CHUNK, NE - base);
    for (int t = tid; t < lim; t += 256) {
        int d = f ? (int)((const long long*)e)[NE + base + t]
                  : ((const int*)e)[NE + base + t];
        atomicAdd(&cnt[d >> BSHIFT], 1);
    }
    __syncthreads();
    if (tid < NBKT && cnt[tid]) atomicAdd(&bktcnt[tid], cnt[tid]);
}

// Pass 1b: scan 196 bucket sizes -> gbase[NBKT+1], init gcursor.
__global__ void scan_bkt(const int* __restrict__ bktcnt, int* __restrict__ gbase,
                         int* __restrict__ gcursor) {
    __shared__ int s[256];
    __shared__ int o[257];
    const int tid = threadIdx.x;
    s[tid] = (tid < NBKT) ? bktcnt[tid] : 0;
    __syncthreads();
    if (tid == 0) {
        int run = 0;
        for (int bkt = 0; bkt < NBKT; ++bkt) { o[bkt] = run; run += s[bkt]; }
        o[NBKT] = run;
    }
    __syncthreads();
    if (tid < NBKT) { gbase[tid] = o[tid]; gcursor[tid] = o[tid]; }
    if (tid == 0) gbase[NBKT] = o[NBKT];
}

// Pass 2: bin 4096 edges into 196 buckets via LDS, flush coalesced runs.
// Packed word: (src << 9) | (dst & 511).  src < 2^17 -> fits 26 bits.
__global__ __launch_bounds__(256) void place_kernel(const void* __restrict__ e,
                                                    const int* __restrict__ flag,
                                                    int* __restrict__ gcursor,
                                                    uint32_t* __restrict__ bkt) {
    __shared__ int cnt[256];
    __shared__ int lbase[256];
    __shared__ int lcur[256];
    __shared__ int gb[256];
    __shared__ int sc[2][256];
    __shared__ uint32_t stage[CHUNK];   // 16 KB
    __shared__ uint8_t  sbkt[CHUNK];    // 4 KB
    const int tid = threadIdx.x;
    const int f = *flag;
    const int base = blockIdx.x * CHUNK;
    const int lim = min(CHUNK, NE - base);

    cnt[tid] = 0;
    __syncthreads();

    int      myb[16];
    uint32_t myp[16];
#pragma unroll
    for (int k = 0; k < 16; ++k) {
        const int t = tid + (k << 8);
        myb[k] = -1;
        if (t < lim) {
            int s, d;
            if (f) {
                s = (int)((const long long*)e)[base + t];
                d = (int)((const long long*)e)[NE + base + t];
            } else {
                s = ((const int*)e)[base + t];
                d = ((const int*)e)[NE + base + t];
            }
            const int bb = d >> BSHIFT;
            myb[k] = bb;
            myp[k] = ((uint32_t)s << BSHIFT) | (uint32_t)(d & BMASK);
            atomicAdd(&cnt[bb], 1);
        }
    }
    __syncthreads();

    // exclusive scan of cnt over 256 entries (Hillis-Steele)
    const int v = cnt[tid];
    int pb = 0;
    sc[0][tid] = v;
    __syncthreads();
#pragma unroll
    for (int off = 1; off < 256; off <<= 1) {
        int t = sc[pb][tid] + ((tid >= off) ? sc[pb][tid - off] : 0);
        pb ^= 1;
        sc[pb][tid] = t;
        __syncthreads();
    }
    lbase[tid] = sc[pb][tid] - v;   // exclusive
    lcur[tid]  = sc[pb][tid] - v;
    if (tid < NBKT && v > 0) gb[tid] = atomicAdd(&gcursor[tid], v);
    __syncthreads();

#pragma unroll
    for (int k = 0; k < 16; ++k) {
        if (myb[k] >= 0) {
            const int p = atomicAdd(&lcur[myb[k]], 1);
            stage[p] = myp[k];
            sbkt[p] = (uint8_t)myb[k];
        }
    }
    __syncthreads();

    for (int i = tid; i < lim; i += 256) {
        const int bb = sbkt[i];
        bkt[gb[bb] + (i - lbase[bb])] = stage[i];
    }
}

// Pass 3: one block per bucket. Exact-dst counting sort fully in LDS,
// coalesced CSR image copy-out + rowptr + dinv.
__global__ __launch_bounds__(512) void build_kernel(const uint32_t* __restrict__ bkt,
                                                    const int* __restrict__ gbase,
                                                    int* __restrict__ rowptr,
                                                    float* __restrict__ dinv,
                                                    int* __restrict__ csr) {
    __shared__ int cnt[512];
    __shared__ int sc[2][512];
    __shared__ uint32_t img[IMG_CAP];   // 64 KB
    const int tid = threadIdx.x;
    const int b = blockIdx.x;
    const int beg = gbase[b];
    const int end = gbase[b + 1];
    const int n = end - beg;
    const int node0 = b << BSHIFT;
    const int nnodes = min(512, NN - node0);

    cnt[tid] = 0;
    __syncthreads();
    for (int i = tid; i < n; i += 512) atomicAdd(&cnt[bkt[beg + i] & BMASK], 1);
    __syncthreads();

    const int deg = cnt[tid];
    int pb = 0;
    sc[0][tid] = deg;
    __syncthreads();
#pragma unroll
    for (int off = 1; off < 512; off <<= 1) {
        int t = sc[pb][tid] + ((tid >= off) ? sc[pb][tid - off] : 0);
        pb ^= 1;
        sc[pb][tid] = t;
        __syncthreads();
    }
    const int excl = sc[pb][tid] - deg;

    if (tid < nnodes) {
        rowptr[node0 + tid] = beg + excl;
        dinv[node0 + tid] = 1.0f / fmaxf((float)deg, 1.0f);
    }
    if (b == 0 && tid == 0) rowptr[NN] = NE;

    __syncthreads();
    cnt[tid] = excl;   // reuse as cursor
    __syncthreads();
    for (int i = tid; i < n; i += 512) {
        const uint32_t w = bkt[beg + i];
        const int p = atomicAdd(&cnt[w & BMASK], 1);
        img[p] = (int)(w >> BSHIFT);
    }
    __syncthreads();
    for (int i = tid; i < n; i += 512) csr[beg + i] = (int)img[i];
}

// ---------------------------------------------------------------------------
// bf16 helpers.  Packed u32 holds 2 bf16 (lo = even elem, hi = odd elem).
__device__ __forceinline__ float bflo(uint32_t v) { return __uint_as_float(v << 16); }
__device__ __forceinline__ float bfhi(uint32_t v) { return __uint_as_float(v & 0xffff0000u); }
// Approximate high element: keep low 16 bits as extra mantissa (rel err < 2^-7
// on this addend only). Saves the v_and per pair in the hot accumulate loop.
__device__ __forceinline__ float bfhi_approx(uint32_t v) { return __uint_as_float(v); }
__device__ __forceinline__ uint32_t bf16rn(float f) {   // round-to-nearest-even
    uint32_t u = __float_as_uint(f);
    return (u + 0x7fffu + ((u >> 16) & 1u)) >> 16;
}
__device__ __forceinline__ uint32_t bfpack(float lo, float hi) {
    return bf16rn(lo) | (bf16rn(hi) << 16);
}

// x (f32) -> packed bf16
__global__ void cvt_bf16(const float4* __restrict__ x4, uint2* __restrict__ o2) {
    const int n = NN * 16;
    for (int i = blockIdx.x * blockDim.x + threadIdx.x; i < n;
         i += gridDim.x * blockDim.x) {
        const float4 v = x4[i];
        uint2 o;
        o.x = bfpack(v.x, v.y);
        o.y = bfpack(v.z, v.w);
        o2[i] = o;
    }
}

// ---------------------------------------------------------------------------
// Fused WL layer on bf16 rows (128 B/row).  TWO nodes per wave: each 32-lane
// half owns one node, 4 edge-groups of 8 lanes; lane reads one 16B granule
// (8 bf16, uint4) per edge; 2-deep unroll (16 rows in flight per wave).
// Each group takes a CONTIGUOUS chunk of the node's edge range, so the
// 2-deep pair csr[e], csr[e+1] shares a cache line (index latency ~halved
// vs interleaved e, e+4).  Reduce: 2 shfl levels (8,16 — within the half).
// MODE 0: out = relu(0.5*(h + agg*dinv));  MODE 1: out = h + relu(...)
__device__ __forceinline__ void acc_bf8(float4& p, float4& r, const uint4 v) {
    p.x += bflo(v.x); p.y += bfhi_approx(v.x);
    p.z += bflo(v.y); p.w += bfhi_approx(v.y);
    r.x += bflo(v.z); r.y += bfhi_approx(v.z);
    r.z += bflo(v.w); r.w += bfhi_approx(v.w);
}

template <int MODE>
__global__ __launch_bounds__(256) void wl_layer_bf(
    const uint4* __restrict__ hb, const int* __restrict__ rowptr,
    const int* __restrict__ csr_src, const float* __restrict__ dinv,
    uint4* __restrict__ outp) {
    const int wid = (blockIdx.x * blockDim.x + threadIdx.x) >> 6;
    const int lane = threadIdx.x & 63;
    const int half = lane >> 5;          // node slot within wave (0..1)
    const int g = (lane >> 3) & 3;       // edge group within half (0..3)
    const int q = lane & 7;              // 16B granule within row (0..7)
    const int node = wid * 2 + half;
    if (node >= NN) return;

    const int beg = rowptr[node];
    const int len = rowptr[node + 1] - beg;
    // contiguous chunk for this group
    int e        = beg + ((len * g) >> 2);
    const int ce = beg + ((len * (g + 1)) >> 2);

    float4 a0 = make_float4(0.f, 0.f, 0.f, 0.f);
    float4 a1 = make_float4(0.f, 0.f, 0.f, 0.f);
    float4 b0 = make_float4(0.f, 0.f, 0.f, 0.f);
    float4 b1 = make_float4(0.f, 0.f, 0.f, 0.f);
    for (; e + 1 < ce; e += 2) {
        const int s0 = csr_src[e];
        const int s1 = csr_src[e + 1];   // same cache line as s0 (mostly)
        const uint4 v0 = hb[(size_t)s0 * 8 + q];
        const uint4 v1 = hb[(size_t)s1 * 8 + q];
        acc_bf8(a0, a1, v0);
        acc_bf8(b0, b1, v1);
    }
    if (e < ce) {
        const uint4 v = hb[(size_t)csr_src[e] * 8 + q];
        acc_bf8(a0, a1, v);
    }
    a0.x += b0.x; a0.y += b0.y; a0.z += b0.z; a0.w += b0.w;
    a1.x += b1.x; a1.y += b1.y; a1.z += b1.z; a1.w += b1.w;

    // reduce across the 4 groups of this half (lanes differing in bits 3,4)
#pragma unroll
    for (int off = 8; off < 32; off <<= 1) {
        a0.x += __shfl_xor(a0.x, off, 64);
        a0.y += __shfl_xor(a0.y, off, 64);
        a0.z += __shfl_xor(a0.z, off, 64);
        a0.w += __shfl_xor(a0.w, off, 64);
        a1.x += __shfl_xor(a1.x, off, 64);
        a1.y += __shfl_xor(a1.y, off, 64);
        a1.z += __shfl_xor(a1.z, off, 64);
        a1.w += __shfl_xor(a1.w, off, 64);
    }
    if (g == 0) {
        const float di = dinv[node];
        const uint4 sv = hb[(size_t)node * 8 + q];
        const float s0 = bflo(sv.x), s1 = bfhi(sv.x);
        const float s2 = bflo(sv.y), s3 = bfhi(sv.y);
        const float s4 = bflo(sv.z), s5 = bfhi(sv.z);
        const float s6 = bflo(sv.w), s7 = bfhi(sv.w);
        float r0, r1, r2, r3, r4, r5, r6, r7;
        if (MODE == 0) {
            r0 = fmaxf(0.5f * (s0 + a0.x * di), 0.f);
            r1 = fmaxf(0.5f * (s1 + a0.y * di), 0.f);
            r2 = fmaxf(0.5f * (s2 + a0.z * di), 0.f);
            r3 = fmaxf(0.5f * (s3 + a0.w * di), 0.f);
            r4 = fmaxf(0.5f * (s4 + a1.x * di), 0.f);
            r5 = fmaxf(0.5f * (s5 + a1.y * di), 0.f);
            r6 = fmaxf(0.5f * (s6 + a1.z * di), 0.f);
            r7 = fmaxf(0.5f * (s7 + a1.w * di), 0.f);
        } else {
            r0 = s0 + fmaxf(0.5f * (s0 + a0.x * di), 0.f);
            r1 = s1 + fmaxf(0.5f * (s1 + a0.y * di), 0.f);
            r2 = s2 + fmaxf(0.5f * (s2 + a0.z * di), 0.f);
            r3 = s3 + fmaxf(0.5f * (s3 + a0.w * di), 0.f);
            r4 = s4 + fmaxf(0.5f * (s4 + a1.x * di), 0.f);
            r5 = s5 + fmaxf(0.5f * (s5 + a1.y * di), 0.f);
            r6 = s6 + fmaxf(0.5f * (s6 + a1.z * di), 0.f);
            r7 = s7 + fmaxf(0.5f * (s7 + a1.w * di), 0.f);
        }
        uint4 o;
        o.x = bfpack(r0, r1);
        o.y = bfpack(r2, r3);
        o.z = bfpack(r4, r5);
        o.w = bfpack(r6, r7);
        outp[(size_t)node * 8 + q] = o;
    }
}

// ---------------------------------------------------------------------------
// out = h @ W + b.  Tiled LDS GEMM; h arrives as packed bf16 (final layer
// output), unpacked exactly to f32 during LDS staging.
constexpr int TROWS = 32;
constexpr int NTILE = NN / TROWS;   // 3125 exact

__device__ __forceinline__ void fma4(float4& acc, float s, const float4& wv) {
    acc.x = fmaf(s, wv.x, acc.x);
    acc.y = fmaf(s, wv.y, acc.y);
    acc.z = fmaf(s, wv.z, acc.z);
    acc.w = fmaf(s, wv.w, acc.w);
}

__global__ __launch_bounds__(256, 4) void matmul_kernel(
    const uint2* __restrict__ hb2, const float4* __restrict__ W4,
    const float4* __restrict__ b4, float4* __restrict__ out4) {
    __shared__ __align__(16) float Ws[D * DO];      // 32 KB, [k][j]
    __shared__ __align__(16) float Hs[TROWS * D];   // 8 KB, [row][k]
    const int tid = threadIdx.x;

    {
        float4* ws4 = (float4*)Ws;
#pragma unroll
        for (int i = 0; i < (D * DO / 4) / 256; ++i)   // 8
            ws4[tid + i * 256] = W4[tid + i * 256];
    }
    const int cg = tid & 31;    // col group: cols cg*4..cg*4+3
    const int rs = tid >> 5;    // row slot: rows rs*4..rs*4+3
    const float4 bv = b4[cg];

    for (int tile = blockIdx.x; tile < NTILE; tile += gridDim.x) {
        const int row0 = tile * TROWS;
        __syncthreads();   // Hs safe to overwrite
        {
            // 32 rows x 16 uint2/row = 512 granules; granule i -> float4 Hs[i]
            float4* hs4 = (float4*)Hs;
#pragma unroll
            for (int i = 0; i < 2; ++i) {
                const int idx = tid + i * 256;          // 0..511
                const uint2 v = hb2[(size_t)row0 * 16 + idx];
                hs4[idx] = make_float4(bflo(v.x), bfhi(v.x), bflo(v.y), bfhi(v.y));
            }
        }
        __syncthreads();

        float4 acc0 = bv, acc1 = bv, acc2 = bv, acc3 = bv;
        const float4* hra = (const float4*)(Hs + (rs * 4 + 0) * D);
        const float4* hrb = (const float4*)(Hs + (rs * 4 + 1) * D);
        const float4* hrc = (const float4*)(Hs + (rs * 4 + 2) * D);
        const float4* hrd = (const float4*)(Hs + (rs * 4 + 3) * D);
        const float4* wsc = (const float4*)Ws + cg;     // stride 32 f4 per k
#pragma unroll
        for (int k4 = 0; k4 < 16; ++k4) {
            const float4 ha = hra[k4];
            const float4 hb = hrb[k4];
            const float4 hc = hrc[k4];
            const float4 hd = hrd[k4];
            const float4 w0 = wsc[(k4 * 4 + 0) * 32];
            const float4 w1 = wsc[(k4 * 4 + 1) * 32];
            const float4 w2 = wsc[(k4 * 4 + 2) * 32];
            const float4 w3 = wsc[(k4 * 4 + 3) * 32];
            fma4(acc0, ha.x, w0); fma4(acc0, ha.y, w1);
            fma4(acc0, ha.z, w2); fma4(acc0, ha.w, w3);
            fma4(acc1, hb.x, w0); fma4(acc1, hb.y, w1);
            fma4(acc1, hb.z, w2); fma4(acc1, hb.w, w3);
            fma4(acc2, hc.x, w0); fma4(acc2, hc.y, w1);
            fma4(acc2, hc.z, w2); fma4(acc2, hc.w, w3);
            fma4(acc3, hd.x, w0); fma4(acc3, hd.y, w1);
            fma4(acc3, hd.z, w2); fma4(acc3, hd.w, w3);
        }
        const int orow = row0 + rs * 4;
        out4[(size_t)(orow + 0) * 32 + cg] = acc0;
        out4[(size_t)(orow + 1) * 32 + cg] = acc1;
        out4[(size_t)(orow + 2) * 32 + cg] = acc2;
        out4[(size_t)(orow + 3) * 32 + cg] = acc3;
    }
}

// ---------------------------------------------------------------------------
extern "C" void kernel_launch(void* const* d_in, const int* in_sizes, int n_in,
                              void* d_out, int out_size, void* d_ws, size_t ws_size,
                              hipStream_t stream) {
    const float* x     = (const float*)d_in[0];
    const void*  edges = d_in[1];
    const float* W     = (const float*)d_in[2];
    const float* b     = (const float*)d_in[3];
    float* out = (float*)d_out;

    char* ws = (char*)d_ws;
    const size_t SZ_BF = (size_t)NN * D * 2;   // 12,800,000 bytes (bf16 rows)
    uint8_t*  xb      = (uint8_t*)ws;                                  // bf16 x
    uint8_t*  hBb     = (uint8_t*)(ws + SZ_BF);
    uint8_t*  hAb     = (uint8_t*)(ws + 2 * SZ_BF);
    uint32_t* bkt     = (uint32_t*)(ws + 3 * SZ_BF);                   // NE u32
    int*      csr     = (int*)(ws + 3 * SZ_BF + (size_t)NE * 4);       // NE ints
    int*      rowptr  = (int*)(ws + 3 * SZ_BF + (size_t)NE * 8);       // NN+1
    float*    dinv    = (float*)(rowptr + NN + 8);                     // NN
    int*      bktcnt  = (int*)(dinv + NN);                             // NBKT
    int*      gbase   = bktcnt + NBKT;                                 // NBKT+1
    int*      gcursor = gbase + NBKT + 1;                              // NBKT
    int*      flag    = gcursor + NBKT;

    const dim3 B(256);

    detect_i64<<<1, 256, 0, stream>>>((const uint32_t*)edges, flag, bktcnt);
    hist_kernel<<<NCHUNK_E, B, 0, stream>>>(edges, flag, bktcnt);
    scan_bkt<<<1, 256, 0, stream>>>(bktcnt, gbase, gcursor);
    place_kernel<<<NCHUNK_E, B, 0, stream>>>(edges, flag, gcursor, bkt);
    build_kernel<<<NBKT, 512, 0, stream>>>(bkt, gbase, rowptr, dinv, csr);

    cvt_bf16<<<2048, B, 0, stream>>>((const float4*)x, (uint2*)xb);

    // 2 nodes per wave -> NN/2 waves -> /4 waves per block = 12500 blocks
    const int LG = (NN / 2 + 3) / 4;   // 12500
    // L0: xb -> hAb; L1: hAb -> hBb; L2: hBb -> hAb; L3: hAb -> hBb (all bf16)
    wl_layer_bf<0><<<LG, B, 0, stream>>>((const uint4*)xb,  rowptr, csr, dinv, (uint4*)hAb);
    wl_layer_bf<1><<<LG, B, 0, stream>>>((const uint4*)hAb, rowptr, csr, dinv, (uint4*)hBb);
    wl_layer_bf<1><<<LG, B, 0, stream>>>((const uint4*)hBb, rowptr, csr, dinv, (uint4*)hAb);
    wl_layer_bf<1><<<LG, B, 0, stream>>>((const uint4*)hAb, rowptr, csr, dinv, (uint4*)hBb);

    matmul_kernel<<<1024, B, 0, stream>>>((const uint2*)hBb, (const float4*)W,
                                          (const float4*)b, (float4*)out);
}